// Round 1
// baseline (462.274 us; speedup 1.0000x reference)
//
#include <hip/hip_runtime.h>

// KPConv simple block: ball query + KPConv + BN(train stats) + LeakyReLU
// B=8, N=4096 -> M=32768; C_IN=64, C_OUT=128, K=15 kernel points, nn<=34.
//
// Key simplification (exact, not approximate): kernel points have
// ||kp|| <= 0.042 and influence w = max(1 - d/0.04, 0), so any neighbor with
// ||rel|| >= 0.082 contributes 0 regardless of the reference's top-k
// bookkeeping (shadow points likewise).  #points within 0.082 is
// Poisson(9.46) => P(>34) ~ 1e-9/query, so an unordered within-0.082 set
// capped at 34 reproduces the reference output.

#define NB     8
#define NPTS   4096
#define M_TOT  32768
#define CIN    64
#define COUT   128
#define NKP    15
#define MAXNN  34
#define R2EFF  (0.082f * 0.082f)
#define KP_INV 25.0f          // 1 / KP_EXTENT(0.04)
#define NEG_SLOPE 0.2f

// ---------------------------------------------------------------------------
// K1: ball query with radius 0.082 (see header).  512 blocks: each block =
// (query chunk of 256) x (candidate j-chunk of 1024) of one batch; candidate
// points staged in LDS as float4; per-query global atomic slot allocation
// (set semantics: order within the neighbor list is irrelevant downstream).
// ---------------------------------------------------------------------------
__global__ __launch_bounds__(256) void k1_ballquery(
    const float* __restrict__ xyz, int* __restrict__ counts,
    unsigned short* __restrict__ nidx)
{
  __shared__ float4 pts[1024];
  const int blk   = blockIdx.x;        // 512 blocks
  const int jc    = blk & 3;           // candidate chunk 0..3
  const int qc    = blk >> 2;          // 0..127
  const int batch = qc >> 4;           // 0..7
  const int qbase = batch * NPTS + (qc & 15) * 256;
  const int jbase = batch * NPTS + jc * 1024;

  for (int idx = threadIdx.x; idx < 3072; idx += 256) {
    int j = idx / 3, comp = idx - j * 3;
    ((float*)pts)[j * 4 + comp] = xyz[(size_t)(jbase + j) * 3 + comp];
  }
  __syncthreads();

  const int q = qbase + threadIdx.x;
  const float qx = xyz[q * 3 + 0];
  const float qy = xyz[q * 3 + 1];
  const float qz = xyz[q * 3 + 2];

  #pragma unroll 4
  for (int j = 0; j < 1024; j++) {
    float4 p = pts[j];
    float dx = p.x - qx, dy = p.y - qy, dz = p.z - qz;
    float d2 = dx * dx + dy * dy + dz * dz;
    if (d2 <= R2EFF) {
      int slot = atomicAdd(&counts[q], 1);
      if (slot < MAXNN) nidx[q * MAXNN + slot] = (unsigned short)(jbase + j);
    }
  }
}

// ---------------------------------------------------------------------------
// K2: KPConv.  4096 blocks x 256 threads; each block owns 8 queries.
// Phase 1 (2 rounds of wave-per-query): gather rel coords, compute influence
// w[nn][k] into LDS (padded 16 per nn for b128 reads), accumulate
// wf[k][c] (lane = c) over neighbors, park in wf_lds[8][960].
// Phase 2: out[q][d] = sum_kc wf[q][kc] * W[kc][d]; thread = (d, q-group of 4),
// W rows streamed from L2 (reused across the block's queries).
// Raw (pre-BN) outputs written to d_out; K3/K4 finish BN+LeakyReLU in place.
// ---------------------------------------------------------------------------
__global__ __launch_bounds__(256) void k2_conv(
    const float* __restrict__ xyz, const float* __restrict__ feats,
    const float* __restrict__ kpts, const float* __restrict__ W,
    const int* __restrict__ counts, const unsigned short* __restrict__ nidx,
    float* __restrict__ out)
{
  __shared__ float wf_lds[8][960];        // 30720 B
  __shared__ float wbuf[4][MAXNN * 16];   //  8704 B  [wave][nn*16+k]
  __shared__ float rel[4][MAXNN][4];      //  2176 B
  __shared__ int   gidx[4][MAXNN];        //   544 B
  __shared__ float kp[NKP][4];            //   240 B

  const int tid  = threadIdx.x;
  const int wave = tid >> 6;
  const int lane = tid & 63;

  if (tid < NKP * 3) {
    int k = tid / 3, c = tid - k * 3;
    kp[k][c] = kpts[tid];
  }

  const int m0 = blockIdx.x * 8;

  for (int r = 0; r < 2; r++) {
    const int q = r * 4 + wave;
    const int m = m0 + q;
    int cnt = counts[m];
    cnt = cnt > MAXNN ? MAXNN : cnt;
    const float qx = xyz[m * 3 + 0];
    const float qy = xyz[m * 3 + 1];
    const float qz = xyz[m * 3 + 2];

    if (lane < cnt) {
      int gg = nidx[m * MAXNN + lane];
      gidx[wave][lane]   = gg;
      rel[wave][lane][0] = xyz[gg * 3 + 0] - qx;
      rel[wave][lane][1] = xyz[gg * 3 + 1] - qy;
      rel[wave][lane][2] = xyz[gg * 3 + 2] - qz;
    }
    __syncthreads();

    // influence weights: 34*16 padded slots (k==15 pad and nn>=cnt get 0)
    for (int pp = lane; pp < MAXNN * 16; pp += 64) {
      int nn = pp >> 4, k = pp & 15;
      float w = 0.f;
      if (k < NKP && nn < cnt) {
        float dx = rel[wave][nn][0] - kp[k][0];
        float dy = rel[wave][nn][1] - kp[k][1];
        float dz = rel[wave][nn][2] - kp[k][2];
        float s  = sqrtf(dx * dx + dy * dy + dz * dz);
        w = fmaxf(1.f - s * KP_INV, 0.f);
      }
      wbuf[wave][pp] = w;
    }
    __syncthreads();

    // wf accumulation: lane = input channel c
    float wf[NKP];
    #pragma unroll
    for (int k = 0; k < NKP; k++) wf[k] = 0.f;
    for (int nn = 0; nn < cnt; nn++) {
      float fc = feats[(size_t)gidx[wave][nn] * CIN + lane];
      const float* wrow = &wbuf[wave][nn * 16];
      #pragma unroll
      for (int k = 0; k < NKP; k++) wf[k] += wrow[k] * fc;
    }
    #pragma unroll
    for (int k = 0; k < NKP; k++) wf_lds[q][k * 64 + lane] = wf[k];
    __syncthreads();
  }

  // ---- Phase 2: out = wf @ W ----
  const int d = tid & 127;
  const int g = tid >> 7;            // query group {0..3} or {4..7}
  float acc0 = 0.f, acc1 = 0.f, acc2 = 0.f, acc3 = 0.f;
  const float* __restrict__ Wp = W + d;
  const float* __restrict__ r0 = wf_lds[g * 4 + 0];
  const float* __restrict__ r1 = wf_lds[g * 4 + 1];
  const float* __restrict__ r2 = wf_lds[g * 4 + 2];
  const float* __restrict__ r3 = wf_lds[g * 4 + 3];

  for (int kc = 0; kc < 960; kc += 4) {
    float w0 = Wp[(kc + 0) * COUT];
    float w1 = Wp[(kc + 1) * COUT];
    float w2 = Wp[(kc + 2) * COUT];
    float w3 = Wp[(kc + 3) * COUT];
    float4 f0 = *(const float4*)&r0[kc];
    float4 f1 = *(const float4*)&r1[kc];
    float4 f2 = *(const float4*)&r2[kc];
    float4 f3 = *(const float4*)&r3[kc];
    acc0 += f0.x * w0 + f0.y * w1 + f0.z * w2 + f0.w * w3;
    acc1 += f1.x * w0 + f1.y * w1 + f1.z * w2 + f1.w * w3;
    acc2 += f2.x * w0 + f2.y * w1 + f2.z * w2 + f2.w * w3;
    acc3 += f3.x * w0 + f3.y * w1 + f3.z * w2 + f3.w * w3;
  }

  const int mo = m0 + g * 4;
  out[(size_t)(mo + 0) * COUT + d] = acc0;
  out[(size_t)(mo + 1) * COUT + d] = acc1;
  out[(size_t)(mo + 2) * COUT + d] = acc2;
  out[(size_t)(mo + 3) * COUT + d] = acc3;
}

// ---------------------------------------------------------------------------
// K3: per-block partial BN sums (256 blocks x 128 rows each)
// ---------------------------------------------------------------------------
__global__ __launch_bounds__(256) void k3_partial(
    const float* __restrict__ out, float* __restrict__ psum,
    float* __restrict__ psumsq)
{
  __shared__ float s[256], sq[256];
  const int blk = blockIdx.x;       // 256
  const int t = threadIdx.x;
  const int d = t & 127;
  const int h = t >> 7;
  float a = 0.f, b = 0.f;
  const int rbase = blk * 128;
  for (int j = 0; j < 64; j++) {
    float v = out[(size_t)(rbase + 2 * j + h) * COUT + d];
    a += v;
    b += v * v;
  }
  s[t] = a; sq[t] = b;
  __syncthreads();
  if (t < 128) {
    psum[blk * 128 + d]   = s[d] + s[d + 128];
    psumsq[blk * 128 + d] = sq[d] + sq[d + 128];
  }
}

// K3b: finalize mu/var -> affine (a, b) per channel
__global__ void k3b_finalize(
    const float* __restrict__ psum, const float* __restrict__ psumsq,
    const float* __restrict__ gamma, const float* __restrict__ beta,
    float* __restrict__ ab)
{
  const int d = threadIdx.x;  // 128 threads
  double s = 0.0, q = 0.0;
  for (int b = 0; b < 256; b++) {
    s += (double)psum[b * 128 + d];
    q += (double)psumsq[b * 128 + d];
  }
  double mu  = s / (double)M_TOT;
  double var = q / (double)M_TOT - mu * mu;   // biased var, matches jnp.var
  float rstd = (float)(1.0 / sqrt(var + 1e-5));
  float a = rstd * gamma[d];
  ab[d]       = a;
  ab[128 + d] = beta[d] - (float)mu * a;
}

// K4: y = a[d]*x + b[d]; LeakyReLU.  float4 grid (4096 blocks x 256 thr)
__global__ __launch_bounds__(256) void k4_norm(
    float* __restrict__ out, const float* __restrict__ ab)
{
  __shared__ float a_s[128], b_s[128];
  if (threadIdx.x < 128) {
    a_s[threadIdx.x] = ab[threadIdx.x];
    b_s[threadIdx.x] = ab[128 + threadIdx.x];
  }
  __syncthreads();
  const int idx = blockIdx.x * 256 + threadIdx.x;   // float4 index
  float4 v = ((const float4*)out)[idx];
  const int d0 = (idx * 4) & 127;
  float y0 = v.x * a_s[d0 + 0] + b_s[d0 + 0];
  float y1 = v.y * a_s[d0 + 1] + b_s[d0 + 1];
  float y2 = v.z * a_s[d0 + 2] + b_s[d0 + 2];
  float y3 = v.w * a_s[d0 + 3] + b_s[d0 + 3];
  v.x = y0 >= 0.f ? y0 : NEG_SLOPE * y0;
  v.y = y1 >= 0.f ? y1 : NEG_SLOPE * y1;
  v.z = y2 >= 0.f ? y2 : NEG_SLOPE * y2;
  v.w = y3 >= 0.f ? y3 : NEG_SLOPE * y3;
  ((float4*)out)[idx] = v;
}

// ---------------------------------------------------------------------------
extern "C" void kernel_launch(void* const* d_in, const int* in_sizes, int n_in,
                              void* d_out, int out_size, void* d_ws,
                              size_t ws_size, hipStream_t stream)
{
  const float* xyz   = (const float*)d_in[0];
  const float* feats = (const float*)d_in[1];
  const float* kpts  = (const float*)d_in[2];
  const float* W     = (const float*)d_in[3];
  const float* gamma = (const float*)d_in[4];
  const float* beta  = (const float*)d_in[5];
  float* out = (float*)d_out;

  char* ws = (char*)d_ws;
  int*            counts = (int*)ws;                         // 131072 B
  unsigned short* nidx   = (unsigned short*)(ws + 131072);   // 2228224 B
  float*          psum   = (float*)(ws + 2359296);           // 131072 B
  float*          psumsq = (float*)(ws + 2490368);           // 131072 B
  float*          ab     = (float*)(ws + 2621440);           // 1024 B

  hipMemsetAsync(counts, 0, M_TOT * sizeof(int), stream);

  k1_ballquery<<<512, 256, 0, stream>>>(xyz, counts, nidx);
  k2_conv<<<M_TOT / 8, 256, 0, stream>>>(xyz, feats, kpts, W, counts, nidx,
                                         out);
  k3_partial<<<256, 256, 0, stream>>>(out, psum, psumsq);
  k3b_finalize<<<1, 128, 0, stream>>>(psum, psumsq, gamma, beta, ab);
  k4_norm<<<(out_size / 4) / 256, 256, 0, stream>>>(out, ab);
}

// Round 2
// 404.391 us; speedup vs baseline: 1.1431x; 1.1431x over previous
//
#include <hip/hip_runtime.h>

// KPConv simple block: ball query + KPConv + BN(train stats) + LeakyReLU
// B=8, N=4096 -> M=32768; C_IN=64, C_OUT=128, K=15 kernel points, nn<=34.
//
// Exact simplification: kernel points have ||kp|| <= 0.042 and influence
// w = max(1 - d/0.04, 0), so any neighbor with ||rel|| >= 0.082 contributes 0;
// the unordered within-0.082 set (cap 34) reproduces the reference top-k.
//
// R2: phase-2 GEMM (out = wf[64x960] @ W[960x128] per block) moved to
// mfma_f32_16x16x32_bf16.  wf kept bf16 in LDS (A layout, row pad 968);
// B-frags read directly from pre-transposed bf16 Wt[n][k] (global, L2-hot).

#define NB     8
#define NPTS   4096
#define M_TOT  32768
#define CIN    64
#define COUT   128
#define NKP    15
#define MAXNN  34
#define R2EFF  (0.082f * 0.082f)
#define KP_INV 25.0f          // 1 / KP_EXTENT(0.04)
#define NEG_SLOPE 0.2f
#define KTOT   960            // NKP * CIN
#define WFPAD  968            // LDS row stride (bf16 elems), 16B-aligned

typedef float f32x4_t __attribute__((ext_vector_type(4)));
typedef short bf16x8_t __attribute__((ext_vector_type(8)));

__device__ __forceinline__ unsigned short f2bf(float f) {
  union { float f; unsigned u; } v; v.f = f;
  unsigned r = v.u + 0x7FFF + ((v.u >> 16) & 1);   // RNE
  return (unsigned short)(r >> 16);
}

// ---------------------------------------------------------------------------
// K1: ball query, radius 0.082, set semantics via atomic slot allocation.
// ---------------------------------------------------------------------------
__global__ __launch_bounds__(256) void k1_ballquery(
    const float* __restrict__ xyz, int* __restrict__ counts,
    unsigned short* __restrict__ nidx)
{
  __shared__ float4 pts[1024];
  const int blk   = blockIdx.x;        // 512 blocks
  const int jc    = blk & 3;
  const int qc    = blk >> 2;
  const int batch = qc >> 4;
  const int qbase = batch * NPTS + (qc & 15) * 256;
  const int jbase = batch * NPTS + jc * 1024;

  for (int idx = threadIdx.x; idx < 3072; idx += 256) {
    int j = idx / 3, comp = idx - j * 3;
    ((float*)pts)[j * 4 + comp] = xyz[(size_t)(jbase + j) * 3 + comp];
  }
  __syncthreads();

  const int q = qbase + threadIdx.x;
  const float qx = xyz[q * 3 + 0];
  const float qy = xyz[q * 3 + 1];
  const float qz = xyz[q * 3 + 2];

  #pragma unroll 4
  for (int j = 0; j < 1024; j++) {
    float4 p = pts[j];
    float dx = p.x - qx, dy = p.y - qy, dz = p.z - qz;
    float d2 = dx * dx + dy * dy + dz * dz;
    if (d2 <= R2EFF) {
      int slot = atomicAdd(&counts[q], 1);
      if (slot < MAXNN) nidx[q * MAXNN + slot] = (unsigned short)(jbase + j);
    }
  }
}

// ---------------------------------------------------------------------------
// KW: one-time W[k][c][d] -> Wt[d][kc] transpose + bf16 convert.
// 60 blocks x 256 thr; lane-consecutive n for coalesced reads, 16B writes.
// ---------------------------------------------------------------------------
__global__ __launch_bounds__(256) void kW_transpose(
    const float* __restrict__ W, unsigned short* __restrict__ Wt)
{
  const int idx = blockIdx.x * 256 + threadIdx.x;  // 15360 = 128 n * 120 kg
  const int n  = idx & 127;
  const int kg = idx >> 7;                         // 0..119
  union { unsigned short s[8]; uint4 v; } u;
  #pragma unroll
  for (int j = 0; j < 8; j++) u.s[j] = f2bf(W[(size_t)(kg * 8 + j) * COUT + n]);
  *(uint4*)&Wt[(size_t)n * KTOT + kg * 8] = u.v;
}

// ---------------------------------------------------------------------------
// K2: fused KPConv.  512 blocks x 256 thr (4 waves), 64 queries/block.
// Phase 1: wave w handles queries w*16..w*16+15; lane nn computes its 15
// influence weights (wbuf), then lane=c accumulates wf[k][c] over neighbors;
// wf stored bf16 in LDS rows (A-operand layout, k-contiguous, pad 968).
// Phase 2: out = wf @ W via 16x16x32 bf16 MFMA.  Wave w owns cols w*32..+31:
// 4 A row-tiles (LDS) x 2 B col-tiles (global Wt), 8 MFMA / K-iter, 30 iters,
// no barriers in the K-loop.
// ---------------------------------------------------------------------------
__global__ __launch_bounds__(256) void k2_conv(
    const float* __restrict__ xyz, const float* __restrict__ feats,
    const float* __restrict__ kpts, const int* __restrict__ counts,
    const unsigned short* __restrict__ nidx,
    const unsigned short* __restrict__ Wt, float* __restrict__ out)
{
  __shared__ short wf[64][WFPAD];         // 123904 B (bf16 bits)
  __shared__ float wbuf[4][MAXNN * 16];   //   8704 B
  __shared__ int   gidx[4][MAXNN];        //    544 B
  __shared__ float kp[NKP][4];            //    240 B

  const int tid = threadIdx.x;
  const int w   = tid >> 6;
  const int L   = tid & 63;
  const int m0  = blockIdx.x * 64;

  if (tid < NKP * 3) {
    int k = tid / 3, c = tid - k * 3;
    kp[k][c] = kpts[tid];
  }
  __syncthreads();

  // ---- Phase 1 ----
  for (int i = 0; i < 16; i++) {
    const int q = w * 16 + i;
    const int m = m0 + q;
    int cnt = counts[m];
    cnt = cnt > MAXNN ? MAXNN : cnt;
    const float qx = xyz[m * 3 + 0];
    const float qy = xyz[m * 3 + 1];
    const float qz = xyz[m * 3 + 2];

    if (L < cnt) {
      const int g = nidx[m * MAXNN + L];
      gidx[w][L] = g;
      const float rx = xyz[g * 3 + 0] - qx;
      const float ry = xyz[g * 3 + 1] - qy;
      const float rz = xyz[g * 3 + 2] - qz;
      #pragma unroll
      for (int k = 0; k < NKP; k++) {
        float dx = rx - kp[k][0], dy = ry - kp[k][1], dz = rz - kp[k][2];
        float s = sqrtf(dx * dx + dy * dy + dz * dz);
        wbuf[w][L * 16 + k] = fmaxf(1.f - s * KP_INV, 0.f);
      }
    }
    __syncthreads();

    float acc[NKP];
    #pragma unroll
    for (int k = 0; k < NKP; k++) acc[k] = 0.f;

    int nn = 0;
    for (; nn + 2 <= cnt; nn += 2) {
      const float f0 = feats[(size_t)gidx[w][nn] * CIN + L];
      const float f1 = feats[(size_t)gidx[w][nn + 1] * CIN + L];
      const float* wr0 = &wbuf[w][nn * 16];
      const float* wr1 = &wbuf[w][nn * 16 + 16];
      float4 a0 = *(const float4*)(wr0 + 0), a1 = *(const float4*)(wr0 + 4);
      float4 a2 = *(const float4*)(wr0 + 8), a3 = *(const float4*)(wr0 + 12);
      float4 b0 = *(const float4*)(wr1 + 0), b1 = *(const float4*)(wr1 + 4);
      float4 b2 = *(const float4*)(wr1 + 8), b3 = *(const float4*)(wr1 + 12);
      acc[0]  += a0.x * f0 + b0.x * f1;  acc[1]  += a0.y * f0 + b0.y * f1;
      acc[2]  += a0.z * f0 + b0.z * f1;  acc[3]  += a0.w * f0 + b0.w * f1;
      acc[4]  += a1.x * f0 + b1.x * f1;  acc[5]  += a1.y * f0 + b1.y * f1;
      acc[6]  += a1.z * f0 + b1.z * f1;  acc[7]  += a1.w * f0 + b1.w * f1;
      acc[8]  += a2.x * f0 + b2.x * f1;  acc[9]  += a2.y * f0 + b2.y * f1;
      acc[10] += a2.z * f0 + b2.z * f1;  acc[11] += a2.w * f0 + b2.w * f1;
      acc[12] += a3.x * f0 + b3.x * f1;  acc[13] += a3.y * f0 + b3.y * f1;
      acc[14] += a3.z * f0 + b3.z * f1;
    }
    if (nn < cnt) {
      const float f0 = feats[(size_t)gidx[w][nn] * CIN + L];
      const float* wr0 = &wbuf[w][nn * 16];
      float4 a0 = *(const float4*)(wr0 + 0), a1 = *(const float4*)(wr0 + 4);
      float4 a2 = *(const float4*)(wr0 + 8), a3 = *(const float4*)(wr0 + 12);
      acc[0]  += a0.x * f0;  acc[1]  += a0.y * f0;
      acc[2]  += a0.z * f0;  acc[3]  += a0.w * f0;
      acc[4]  += a1.x * f0;  acc[5]  += a1.y * f0;
      acc[6]  += a1.z * f0;  acc[7]  += a1.w * f0;
      acc[8]  += a2.x * f0;  acc[9]  += a2.y * f0;
      acc[10] += a2.z * f0;  acc[11] += a2.w * f0;
      acc[12] += a3.x * f0;  acc[13] += a3.y * f0;
      acc[14] += a3.z * f0;
    }

    #pragma unroll
    for (int k = 0; k < NKP; k++)
      wf[q][k * 64 + L] = (short)f2bf(acc[k]);
    __syncthreads();
  }

  // ---- Phase 2: MFMA GEMM out[64][128] = wf[64][960] @ W[960][128] ----
  const int ln = L & 15;
  const int kh = L >> 4;            // 0..3
  const int colbase = w * 32;

  f32x4_t acc2[4][2];
  #pragma unroll
  for (int r = 0; r < 4; r++)
    #pragma unroll
    for (int c = 0; c < 2; c++)
      acc2[r][c] = (f32x4_t){0.f, 0.f, 0.f, 0.f};

  const unsigned short* Bp0 = &Wt[(size_t)(colbase + ln) * KTOT + kh * 8];
  const unsigned short* Bp1 = Bp0 + 16 * KTOT;
  const short* Ap0 = &wf[ln][kh * 8];
  const short* Ap1 = &wf[16 + ln][kh * 8];
  const short* Ap2 = &wf[32 + ln][kh * 8];
  const short* Ap3 = &wf[48 + ln][kh * 8];

  #pragma unroll 2
  for (int kk = 0; kk < 30; kk++) {
    const int ko = kk * 32;
    bf16x8_t b0 = *(const bf16x8_t*)(Bp0 + ko);
    bf16x8_t b1 = *(const bf16x8_t*)(Bp1 + ko);
    bf16x8_t a0 = *(const bf16x8_t*)(Ap0 + ko);
    bf16x8_t a1 = *(const bf16x8_t*)(Ap1 + ko);
    bf16x8_t a2 = *(const bf16x8_t*)(Ap2 + ko);
    bf16x8_t a3 = *(const bf16x8_t*)(Ap3 + ko);
    acc2[0][0] = __builtin_amdgcn_mfma_f32_16x16x32_bf16(a0, b0, acc2[0][0], 0, 0, 0);
    acc2[1][0] = __builtin_amdgcn_mfma_f32_16x16x32_bf16(a1, b0, acc2[1][0], 0, 0, 0);
    acc2[2][0] = __builtin_amdgcn_mfma_f32_16x16x32_bf16(a2, b0, acc2[2][0], 0, 0, 0);
    acc2[3][0] = __builtin_amdgcn_mfma_f32_16x16x32_bf16(a3, b0, acc2[3][0], 0, 0, 0);
    acc2[0][1] = __builtin_amdgcn_mfma_f32_16x16x32_bf16(a0, b1, acc2[0][1], 0, 0, 0);
    acc2[1][1] = __builtin_amdgcn_mfma_f32_16x16x32_bf16(a1, b1, acc2[1][1], 0, 0, 0);
    acc2[2][1] = __builtin_amdgcn_mfma_f32_16x16x32_bf16(a2, b1, acc2[2][1], 0, 0, 0);
    acc2[3][1] = __builtin_amdgcn_mfma_f32_16x16x32_bf16(a3, b1, acc2[3][1], 0, 0, 0);
  }

  // C/D layout (m89/m91 verified): col = lane&15, row = (lane>>4)*4 + reg
  #pragma unroll
  for (int r = 0; r < 4; r++) {
    #pragma unroll
    for (int c = 0; c < 2; c++) {
      #pragma unroll
      for (int j = 0; j < 4; j++) {
        const int row = r * 16 + kh * 4 + j;
        const int col = colbase + c * 16 + ln;
        out[(size_t)(m0 + row) * COUT + col] = acc2[r][c][j];
      }
    }
  }
}

// ---------------------------------------------------------------------------
// K3: per-block partial BN sums (64 blocks x 512 rows each)
// ---------------------------------------------------------------------------
__global__ __launch_bounds__(256) void k3_partial(
    const float* __restrict__ out, float* __restrict__ psum,
    float* __restrict__ psumsq)
{
  __shared__ float s[256], sq[256];
  const int blk = blockIdx.x;       // 64
  const int t = threadIdx.x;
  const int d = t & 127;
  const int h = t >> 7;
  float a = 0.f, b = 0.f;
  const int rbase = blk * 512;
  for (int j = 0; j < 256; j++) {
    float v = out[(size_t)(rbase + 2 * j + h) * COUT + d];
    a += v;
    b += v * v;
  }
  s[t] = a; sq[t] = b;
  __syncthreads();
  if (t < 128) {
    psum[blk * 128 + d]   = s[d] + s[d + 128];
    psumsq[blk * 128 + d] = sq[d] + sq[d + 128];
  }
}

// K3b: finalize mu/var -> per-channel affine (a, b)
__global__ void k3b_finalize(
    const float* __restrict__ psum, const float* __restrict__ psumsq,
    const float* __restrict__ gamma, const float* __restrict__ beta,
    float* __restrict__ ab)
{
  const int d = threadIdx.x;  // 128 threads
  double s = 0.0, q = 0.0;
  for (int b = 0; b < 64; b++) {
    s += (double)psum[b * 128 + d];
    q += (double)psumsq[b * 128 + d];
  }
  double mu  = s / (double)M_TOT;
  double var = q / (double)M_TOT - mu * mu;   // biased var (jnp.var)
  float rstd = (float)(1.0 / sqrt(var + 1e-5));
  float a = rstd * gamma[d];
  ab[d]       = a;
  ab[128 + d] = beta[d] - (float)mu * a;
}

// K4: y = a[d]*x + b[d]; LeakyReLU
__global__ __launch_bounds__(256) void k4_norm(
    float* __restrict__ out, const float* __restrict__ ab)
{
  __shared__ float a_s[128], b_s[128];
  if (threadIdx.x < 128) {
    a_s[threadIdx.x] = ab[threadIdx.x];
    b_s[threadIdx.x] = ab[128 + threadIdx.x];
  }
  __syncthreads();
  const int idx = blockIdx.x * 256 + threadIdx.x;   // float4 index
  float4 v = ((const float4*)out)[idx];
  const int d0 = (idx * 4) & 127;
  float y0 = v.x * a_s[d0 + 0] + b_s[d0 + 0];
  float y1 = v.y * a_s[d0 + 1] + b_s[d0 + 1];
  float y2 = v.z * a_s[d0 + 2] + b_s[d0 + 2];
  float y3 = v.w * a_s[d0 + 3] + b_s[d0 + 3];
  v.x = y0 >= 0.f ? y0 : NEG_SLOPE * y0;
  v.y = y1 >= 0.f ? y1 : NEG_SLOPE * y1;
  v.z = y2 >= 0.f ? y2 : NEG_SLOPE * y2;
  v.w = y3 >= 0.f ? y3 : NEG_SLOPE * y3;
  ((float4*)out)[idx] = v;
}

// ---------------------------------------------------------------------------
extern "C" void kernel_launch(void* const* d_in, const int* in_sizes, int n_in,
                              void* d_out, int out_size, void* d_ws,
                              size_t ws_size, hipStream_t stream)
{
  const float* xyz   = (const float*)d_in[0];
  const float* feats = (const float*)d_in[1];
  const float* kpts  = (const float*)d_in[2];
  const float* W     = (const float*)d_in[3];
  const float* gamma = (const float*)d_in[4];
  const float* beta  = (const float*)d_in[5];
  float* out = (float*)d_out;

  char* ws = (char*)d_ws;
  int*            counts = (int*)ws;                         //  131072 B
  unsigned short* nidx   = (unsigned short*)(ws + 131072);   // 2228224 B
  float*          psum   = (float*)(ws + 2359296);           //   32768 B
  float*          psumsq = (float*)(ws + 2392064);           //   32768 B
  float*          ab     = (float*)(ws + 2424832);           //    1024 B
  unsigned short* Wt     = (unsigned short*)(ws + 2425856);  //  245760 B

  hipMemsetAsync(counts, 0, M_TOT * sizeof(int), stream);

  kW_transpose<<<60, 256, 0, stream>>>(W, Wt);
  k1_ballquery<<<512, 256, 0, stream>>>(xyz, counts, nidx);
  k2_conv<<<512, 256, 0, stream>>>(xyz, feats, kpts, counts, nidx, Wt, out);
  k3_partial<<<64, 256, 0, stream>>>(out, psum, psumsq);
  k3b_finalize<<<1, 128, 0, stream>>>(psum, psumsq, gamma, beta, ab);
  k4_norm<<<(out_size / 4) / 256, 256, 0, stream>>>(out, ab);
}

// Round 3
// 286.630 us; speedup vs baseline: 1.6128x; 1.4108x over previous
//
#include <hip/hip_runtime.h>

// KPConv simple block: ball query + KPConv + BN(train stats) + LeakyReLU
// B=8, N=4096 -> M=32768; C_IN=64, C_OUT=128, K=15 kernel points, nn<=34.
//
// Exact simplification: kernel points have ||kp|| <= 0.042 and influence
// w = max(1 - d/0.04, 0), so any neighbor with ||rel|| >= 0.082 contributes 0;
// the unordered within-0.082 set (cap 34) reproduces the reference top-k.
//
// R3: k1 atomic-free (per-(query,chunk) private lists; the R2 in-loop
// atomicAdd-with-return was a ~700-cyc dependency per hit -> 164 us).
// k2 at 16 queries/block (69 KB LDS -> 2 blocks/CU) with dense parallel
// weight phase (one barrier) + MFMA phase 2.

#define NB     8
#define NPTS   4096
#define M_TOT  32768
#define CIN    64
#define COUT   128
#define NKP    15
#define MAXNN  34
#define CAP4   28             // per-chunk neighbor cap (Poisson(2.36) tail ~1e-16)
#define R2EFF  (0.082f * 0.082f)
#define KP_INV 25.0f          // 1 / KP_EXTENT(0.04)
#define NEG_SLOPE 0.2f
#define KTOT   960            // NKP * CIN
#define WFPAD  968            // LDS row stride (bf16 elems), 16B-aligned

typedef float f32x4_t __attribute__((ext_vector_type(4)));
typedef short bf16x8_t __attribute__((ext_vector_type(8)));

__device__ __forceinline__ unsigned short f2bf(float f) {
  union { float f; unsigned u; } v; v.f = f;
  unsigned r = v.u + 0x7FFF + ((v.u >> 16) & 1);   // RNE
  return (unsigned short)(r >> 16);
}

// ---------------------------------------------------------------------------
// K1: ball query, radius 0.082.  512 blocks = (batch 8) x (qgroup 16) x
// (cand chunk 4).  Each thread owns one (query, chunk): private 28-slot
// output region, fire-and-forget stores, NO atomics anywhere.
// ---------------------------------------------------------------------------
__global__ __launch_bounds__(256) void k1_ballquery(
    const float* __restrict__ xyz, int* __restrict__ counts4,
    unsigned short* __restrict__ nidx4)
{
  __shared__ float4 pts[1024];
  const int blk   = blockIdx.x;        // 512 blocks
  const int jc    = blk & 3;
  const int qc    = blk >> 2;
  const int batch = qc >> 4;
  const int qbase = batch * NPTS + (qc & 15) * 256;
  const int jbase = batch * NPTS + jc * 1024;

  // stage 1024 candidates as float4 (mild write conflicts, once per block)
  for (int p = threadIdx.x; p < 1024; p += 256) {
    const float* s = &xyz[(size_t)(jbase + p) * 3];
    pts[p] = make_float4(s[0], s[1], s[2], 0.f);
  }
  __syncthreads();

  const int q  = qbase + threadIdx.x;
  const float qx = xyz[q * 3 + 0];
  const float qy = xyz[q * 3 + 1];
  const float qz = xyz[q * 3 + 2];

  int cnt = 0;
  const size_t obase = ((size_t)q * 4 + jc) * CAP4;

  #pragma unroll 4
  for (int j = 0; j < 1024; j++) {
    float4 p = pts[j];
    float dx = p.x - qx, dy = p.y - qy, dz = p.z - qz;
    float d2 = dx * dx + dy * dy + dz * dz;
    if (d2 <= R2EFF) {
      if (cnt < CAP4) nidx4[obase + cnt] = (unsigned short)(jbase + j);
      cnt++;
    }
  }
  counts4[q * 4 + jc] = cnt > CAP4 ? CAP4 : cnt;
}

// ---------------------------------------------------------------------------
// KW: one-time W[k][c][d] -> Wt[d][kc] transpose + bf16 convert.
// ---------------------------------------------------------------------------
__global__ __launch_bounds__(256) void kW_transpose(
    const float* __restrict__ W, unsigned short* __restrict__ Wt)
{
  const int idx = blockIdx.x * 256 + threadIdx.x;  // 15360 = 128 n * 120 kg
  const int n  = idx & 127;
  const int kg = idx >> 7;                         // 0..119
  union { unsigned short s[8]; uint4 v; } u;
  #pragma unroll
  for (int j = 0; j < 8; j++) u.s[j] = f2bf(W[(size_t)(kg * 8 + j) * COUT + n]);
  *(uint4*)&Wt[(size_t)n * KTOT + kg * 8] = u.v;
}

// ---------------------------------------------------------------------------
// K2: fused KPConv.  2048 blocks x 256 thr (4 waves), 16 queries/block,
// ~69 KB LDS -> 2 blocks/CU.
//  a) merge 4 chunk lists -> gidx[q][nn] (+prefix), one barrier
//  b) dense weight phase: 544 (q,nn) pairs across 256 threads -> w2 LDS
//  c) accumulation: wave w owns queries w*4..w*4+3, lane = channel;
//     wf rows stored bf16 (A-operand layout)
//  d) MFMA 16x16x32 GEMM: wave w owns cols w*32..+31; B-frags from global Wt
// ---------------------------------------------------------------------------
__global__ __launch_bounds__(256, 2) void k2_conv(
    const float* __restrict__ xyz, const float* __restrict__ feats,
    const float* __restrict__ kpts, const int* __restrict__ counts4,
    const unsigned short* __restrict__ nidx4,
    const unsigned short* __restrict__ Wt, float* __restrict__ out)
{
  __shared__ short wf[16][WFPAD];        // 30976 B
  __shared__ float w2[16][MAXNN][16];    // 34816 B
  __shared__ int   gidx[16][MAXNN];      //  2176 B
  __shared__ float qxyz[48];             //   192 B
  __shared__ float kp[NKP][4];           //   240 B
  __shared__ int   cnts[16];             //    64 B
  __shared__ int   offs[16][4];          //   256 B

  const int tid = threadIdx.x;
  const int w   = tid >> 6;
  const int L   = tid & 63;
  const int m0  = blockIdx.x * 16;

  if (tid < NKP * 3) {
    int k = tid / 3, c = tid - k * 3;
    kp[k][c] = kpts[tid];
  }
  if (tid >= 64 && tid < 112) qxyz[tid - 64] = xyz[m0 * 3 + (tid - 64)];
  if (tid < 16) {
    const int m = m0 + tid;
    int c0 = counts4[m * 4 + 0], c1 = counts4[m * 4 + 1];
    int c2 = counts4[m * 4 + 2], c3 = counts4[m * 4 + 3];
    offs[tid][0] = 0; offs[tid][1] = c0;
    offs[tid][2] = c0 + c1; offs[tid][3] = c0 + c1 + c2;
    int t = c0 + c1 + c2 + c3;
    cnts[tid] = t > MAXNN ? MAXNN : t;
  }
  __syncthreads();

  // ---- merge chunk lists ----
  if (tid < 64) {
    const int q = tid >> 2, c = tid & 3;
    const int m = m0 + q;
    const int cc = counts4[m * 4 + c];
    const int off = offs[q][c];
    const size_t sbase = ((size_t)m * 4 + c) * CAP4;
    for (int i = 0; i < cc; i++) {
      int dst = off + i;
      if (dst < MAXNN) gidx[q][dst] = (int)nidx4[sbase + i];
    }
  }
  __syncthreads();

  // ---- dense weight phase: 544 pairs over 256 threads ----
  #pragma unroll
  for (int rep = 0; rep < 3; rep++) {
    const int p = rep * 256 + tid;
    if (p < 16 * MAXNN) {
      const int q  = (p * 241) >> 13;     // p / 34
      const int nn = p - q * MAXNN;
      if (nn < cnts[q]) {
        const int g = gidx[q][nn];
        const float rx = xyz[g * 3 + 0] - qxyz[q * 3 + 0];
        const float ry = xyz[g * 3 + 1] - qxyz[q * 3 + 1];
        const float rz = xyz[g * 3 + 2] - qxyz[q * 3 + 2];
        float wv[16];
        #pragma unroll
        for (int k = 0; k < NKP; k++) {
          float dx = rx - kp[k][0], dy = ry - kp[k][1], dz = rz - kp[k][2];
          float s = sqrtf(dx * dx + dy * dy + dz * dz);
          wv[k] = fmaxf(1.f - s * KP_INV, 0.f);
        }
        wv[15] = 0.f;
        float* dst = w2[q][nn];
        *(float4*)(dst + 0)  = *(float4*)(wv + 0);
        *(float4*)(dst + 4)  = *(float4*)(wv + 4);
        *(float4*)(dst + 8)  = *(float4*)(wv + 8);
        *(float4*)(dst + 12) = *(float4*)(wv + 12);
      }
    }
  }
  __syncthreads();

  // ---- accumulation: wave w -> queries w*4..w*4+3, lane = channel ----
  for (int qi = 0; qi < 4; qi++) {
    const int q = w * 4 + qi;
    const int cnt = cnts[q];
    float acc[NKP];
    #pragma unroll
    for (int k = 0; k < NKP; k++) acc[k] = 0.f;

    int nn = 0;
    for (; nn + 2 <= cnt; nn += 2) {
      const float f0 = feats[(size_t)gidx[q][nn] * CIN + L];
      const float f1 = feats[(size_t)gidx[q][nn + 1] * CIN + L];
      const float* r0 = w2[q][nn];
      const float* r1 = w2[q][nn + 1];
      float4 a0 = *(const float4*)(r0 + 0), a1 = *(const float4*)(r0 + 4);
      float4 a2 = *(const float4*)(r0 + 8), a3 = *(const float4*)(r0 + 12);
      float4 b0 = *(const float4*)(r1 + 0), b1 = *(const float4*)(r1 + 4);
      float4 b2 = *(const float4*)(r1 + 8), b3 = *(const float4*)(r1 + 12);
      acc[0]  += a0.x * f0 + b0.x * f1;  acc[1]  += a0.y * f0 + b0.y * f1;
      acc[2]  += a0.z * f0 + b0.z * f1;  acc[3]  += a0.w * f0 + b0.w * f1;
      acc[4]  += a1.x * f0 + b1.x * f1;  acc[5]  += a1.y * f0 + b1.y * f1;
      acc[6]  += a1.z * f0 + b1.z * f1;  acc[7]  += a1.w * f0 + b1.w * f1;
      acc[8]  += a2.x * f0 + b2.x * f1;  acc[9]  += a2.y * f0 + b2.y * f1;
      acc[10] += a2.z * f0 + b2.z * f1;  acc[11] += a2.w * f0 + b2.w * f1;
      acc[12] += a3.x * f0 + b3.x * f1;  acc[13] += a3.y * f0 + b3.y * f1;
      acc[14] += a3.z * f0 + b3.z * f1;
    }
    if (nn < cnt) {
      const float f0 = feats[(size_t)gidx[q][nn] * CIN + L];
      const float* r0 = w2[q][nn];
      float4 a0 = *(const float4*)(r0 + 0), a1 = *(const float4*)(r0 + 4);
      float4 a2 = *(const float4*)(r0 + 8), a3 = *(const float4*)(r0 + 12);
      acc[0]  += a0.x * f0;  acc[1]  += a0.y * f0;
      acc[2]  += a0.z * f0;  acc[3]  += a0.w * f0;
      acc[4]  += a1.x * f0;  acc[5]  += a1.y * f0;
      acc[6]  += a1.z * f0;  acc[7]  += a1.w * f0;
      acc[8]  += a2.x * f0;  acc[9]  += a2.y * f0;
      acc[10] += a2.z * f0;  acc[11] += a2.w * f0;
      acc[12] += a3.x * f0;  acc[13] += a3.y * f0;
      acc[14] += a3.z * f0;
    }
    #pragma unroll
    for (int k = 0; k < NKP; k++)
      wf[q][k * 64 + L] = (short)f2bf(acc[k]);
  }
  __syncthreads();

  // ---- MFMA GEMM: out[16][128] = wf[16][960] @ W[960][128] ----
  const int ln = L & 15;
  const int kh = L >> 4;            // 0..3
  const int colbase = w * 32;

  f32x4_t acc2[2];
  acc2[0] = (f32x4_t){0.f, 0.f, 0.f, 0.f};
  acc2[1] = (f32x4_t){0.f, 0.f, 0.f, 0.f};

  const unsigned short* Bp0 = &Wt[(size_t)(colbase + ln) * KTOT + kh * 8];
  const unsigned short* Bp1 = Bp0 + 16 * KTOT;
  const short* Ap = &wf[ln][kh * 8];

  #pragma unroll 3
  for (int kk = 0; kk < 30; kk++) {
    const int ko = kk * 32;
    bf16x8_t b0 = *(const bf16x8_t*)(Bp0 + ko);
    bf16x8_t b1 = *(const bf16x8_t*)(Bp1 + ko);
    bf16x8_t a0 = *(const bf16x8_t*)(Ap + ko);
    acc2[0] = __builtin_amdgcn_mfma_f32_16x16x32_bf16(a0, b0, acc2[0], 0, 0, 0);
    acc2[1] = __builtin_amdgcn_mfma_f32_16x16x32_bf16(a0, b1, acc2[1], 0, 0, 0);
  }

  // C/D layout: col = lane&15, row = (lane>>4)*4 + reg
  #pragma unroll
  for (int c = 0; c < 2; c++) {
    #pragma unroll
    for (int j = 0; j < 4; j++) {
      const int row = kh * 4 + j;
      const int col = colbase + c * 16 + ln;
      out[(size_t)(m0 + row) * COUT + col] = acc2[c][j];
    }
  }
}

// ---------------------------------------------------------------------------
// K3: per-block partial BN sums (128 blocks x 256 rows each)
// ---------------------------------------------------------------------------
__global__ __launch_bounds__(256) void k3_partial(
    const float* __restrict__ out, float* __restrict__ psum,
    float* __restrict__ psumsq)
{
  __shared__ float s[256], sq[256];
  const int blk = blockIdx.x;       // 128
  const int t = threadIdx.x;
  const int d = t & 127;
  const int h = t >> 7;
  float a = 0.f, b = 0.f;
  const int rbase = blk * 256;
  for (int j = 0; j < 128; j++) {
    float v = out[(size_t)(rbase + 2 * j + h) * COUT + d];
    a += v;
    b += v * v;
  }
  s[t] = a; sq[t] = b;
  __syncthreads();
  if (t < 128) {
    psum[blk * 128 + d]   = s[d] + s[d + 128];
    psumsq[blk * 128 + d] = sq[d] + sq[d + 128];
  }
}

// K3b: finalize mu/var -> per-channel affine (a, b)
__global__ void k3b_finalize(
    const float* __restrict__ psum, const float* __restrict__ psumsq,
    const float* __restrict__ gamma, const float* __restrict__ beta,
    float* __restrict__ ab)
{
  const int d = threadIdx.x;  // 128 threads
  double s = 0.0, q = 0.0;
  for (int b = 0; b < 128; b++) {
    s += (double)psum[b * 128 + d];
    q += (double)psumsq[b * 128 + d];
  }
  double mu  = s / (double)M_TOT;
  double var = q / (double)M_TOT - mu * mu;   // biased var (jnp.var)
  float rstd = (float)(1.0 / sqrt(var + 1e-5));
  float a = rstd * gamma[d];
  ab[d]       = a;
  ab[128 + d] = beta[d] - (float)mu * a;
}

// K4: y = a[d]*x + b[d]; LeakyReLU
__global__ __launch_bounds__(256) void k4_norm(
    float* __restrict__ out, const float* __restrict__ ab)
{
  __shared__ float a_s[128], b_s[128];
  if (threadIdx.x < 128) {
    a_s[threadIdx.x] = ab[threadIdx.x];
    b_s[threadIdx.x] = ab[128 + threadIdx.x];
  }
  __syncthreads();
  const int idx = blockIdx.x * 256 + threadIdx.x;   // float4 index
  float4 v = ((const float4*)out)[idx];
  const int d0 = (idx * 4) & 127;
  float y0 = v.x * a_s[d0 + 0] + b_s[d0 + 0];
  float y1 = v.y * a_s[d0 + 1] + b_s[d0 + 1];
  float y2 = v.z * a_s[d0 + 2] + b_s[d0 + 2];
  float y3 = v.w * a_s[d0 + 3] + b_s[d0 + 3];
  v.x = y0 >= 0.f ? y0 : NEG_SLOPE * y0;
  v.y = y1 >= 0.f ? y1 : NEG_SLOPE * y1;
  v.z = y2 >= 0.f ? y2 : NEG_SLOPE * y2;
  v.w = y3 >= 0.f ? y3 : NEG_SLOPE * y3;
  ((float4*)out)[idx] = v;
}

// ---------------------------------------------------------------------------
extern "C" void kernel_launch(void* const* d_in, const int* in_sizes, int n_in,
                              void* d_out, int out_size, void* d_ws,
                              size_t ws_size, hipStream_t stream)
{
  const float* xyz   = (const float*)d_in[0];
  const float* feats = (const float*)d_in[1];
  const float* kpts  = (const float*)d_in[2];
  const float* W     = (const float*)d_in[3];
  const float* gamma = (const float*)d_in[4];
  const float* beta  = (const float*)d_in[5];
  float* out = (float*)d_out;

  char* ws = (char*)d_ws;
  int*            counts4 = (int*)ws;                         //  524288 B
  unsigned short* nidx4   = (unsigned short*)(ws + 524288);   // 7340032 B
  float*          psum    = (float*)(ws + 7864320);           //   65536 B
  float*          psumsq  = (float*)(ws + 7929856);           //   65536 B
  float*          ab      = (float*)(ws + 7995392);           //    1024 B
  unsigned short* Wt      = (unsigned short*)(ws + 7996416);  //  245760 B

  kW_transpose<<<60, 256, 0, stream>>>(W, Wt);
  k1_ballquery<<<512, 256, 0, stream>>>(xyz, counts4, nidx4);
  k2_conv<<<2048, 256, 0, stream>>>(xyz, feats, kpts, counts4, nidx4, Wt, out);
  k3_partial<<<128, 256, 0, stream>>>(out, psum, psumsq);
  k3b_finalize<<<1, 128, 0, stream>>>(psum, psumsq, gamma, beta, ab);
  k4_norm<<<(out_size / 4) / 256, 256, 0, stream>>>(out, ab);
}

// Round 4
// 220.990 us; speedup vs baseline: 2.0918x; 1.2970x over previous
//
#include <hip/hip_runtime.h>

// KPConv simple block: grid-based ball query + KPConv(MFMA) + BN + LeakyReLU
// B=8, N=4096 -> M=32768; C_IN=64, C_OUT=128, K=15 kernel pts, nn<=34.
//
// Exact simplification: influence w = max(1 - d/0.04, 0) with ||kp||<=0.042
// => any neighbor with ||rel|| >= 0.082 contributes 0; unordered within-0.082
// set (cap 34) == reference top-k result.
//
// R4: 12^3 spatial grid (cell 0.0833 >= 0.082 => 27-cell window, searched as
// 9 contiguous x-ranges).  Points counting-sorted by cell: sorted xyz (f4),
// sorted bf16 feats (4.2 MB, L2-resident).  Ball query fused into k2
// prologue; k2 blocks own 16 spatially-clustered queries => L2-hot gathers.
// BN partials fused into k2 epilogue (shfl + global fp32 atomics).

#define NB     8
#define NPTS   4096
#define M_TOT  32768
#define CIN    64
#define COUT   128
#define NKP    15
#define MAXNN  34
#define GRID   12
#define NCELL  1728            // 12^3
#define R2EFF  (0.082f * 0.082f)
#define KP_INV 25.0f           // 1 / KP_EXTENT(0.04)
#define NEG_SLOPE 0.2f
#define KTOT   960             // NKP * CIN
#define WFPAD  968             // LDS wf row stride (bf16), 16B-aligned

typedef float f32x4_t __attribute__((ext_vector_type(4)));
typedef short bf16x8_t __attribute__((ext_vector_type(8)));

__device__ __forceinline__ unsigned short f2bf(float f) {
  union { float f; unsigned u; } v; v.f = f;
  unsigned r = v.u + 0x7FFF + ((v.u >> 16) & 1);   // RNE
  return (unsigned short)(r >> 16);
}
__device__ __forceinline__ float bf2f(unsigned short s) {
  union { unsigned u; float f; } v; v.u = ((unsigned)s) << 16; return v.f;
}
__device__ __forceinline__ int cell_of(float x, float y, float z) {
  int cx = (int)(x * 12.f); cx = cx > 11 ? 11 : cx;
  int cy = (int)(y * 12.f); cy = cy > 11 ? 11 : cy;
  int cz = (int)(z * 12.f); cz = cz > 11 ? 11 : cz;
  return (cz * 12 + cy) * 12 + cx;
}

// ---------------------------------------------------------------------------
// K0a: per-cell histogram (32k independent atomics, avg contention 2.4)
// ---------------------------------------------------------------------------
__global__ __launch_bounds__(256) void k0a_hist(
    const float* __restrict__ xyz, int* __restrict__ cellcnt)
{
  const int pt = blockIdx.x * 256 + threadIdx.x;
  const float x = xyz[pt * 3], y = xyz[pt * 3 + 1], z = xyz[pt * 3 + 2];
  const int b = pt >> 12;
  atomicAdd(&cellcnt[b * NCELL + cell_of(x, y, z)], 1);
}

// ---------------------------------------------------------------------------
// K0b: blocks 0..7 = per-batch exclusive scan -> cellstart[b][0..1728];
//      blocks 8..67 = W transpose+bf16 (fused to save a dispatch).
// ---------------------------------------------------------------------------
__global__ __launch_bounds__(256) void k0b_scan_kW(
    const int* __restrict__ cellcnt, int* __restrict__ cellstart,
    const float* __restrict__ W, unsigned short* __restrict__ Wt)
{
  if (blockIdx.x >= 8) {
    const int idx = (blockIdx.x - 8) * 256 + threadIdx.x;  // 15360
    const int n = idx & 127, kg = idx >> 7;
    union { unsigned short s[8]; uint4 v; } u;
    #pragma unroll
    for (int j = 0; j < 8; j++)
      u.s[j] = f2bf(W[(size_t)(kg * 8 + j) * COUT + n]);
    *(uint4*)&Wt[(size_t)n * KTOT + kg * 8] = u.v;
    return;
  }
  __shared__ int ps[256];
  const int b = blockIdx.x, t = threadIdx.x;
  int local[7], s = 0;
  #pragma unroll
  for (int i = 0; i < 7; i++) {
    const int cid = t * 7 + i;
    const int c = (cid < NCELL) ? cellcnt[b * NCELL + cid] : 0;
    local[i] = c; s += c;
  }
  ps[t] = s; __syncthreads();
  for (int off = 1; off < 256; off <<= 1) {
    int v = (t >= off) ? ps[t - off] : 0;
    __syncthreads();
    ps[t] += v;
    __syncthreads();
  }
  int run = ps[t] - s;    // exclusive prefix
  #pragma unroll
  for (int i = 0; i < 7; i++) {
    const int cid = t * 7 + i;
    if (cid < NCELL) { cellstart[b * 1729 + cid] = run; run += local[i]; }
  }
  if (t == 255) cellstart[b * 1729 + NCELL] = ps[255];   // = 4096
}

// ---------------------------------------------------------------------------
// K0c: counting-sort scatter -> qorder (orig idx) + sorted xyz float4
// ---------------------------------------------------------------------------
__global__ __launch_bounds__(256) void k0c_scatter(
    const float* __restrict__ xyz, const int* __restrict__ cellstart,
    int* __restrict__ cellfill, int* __restrict__ qorder,
    float4* __restrict__ xyzs)
{
  const int pt = blockIdx.x * 256 + threadIdx.x;
  const float x = xyz[pt * 3], y = xyz[pt * 3 + 1], z = xyz[pt * 3 + 2];
  const int b = pt >> 12;
  const int cid = cell_of(x, y, z);
  const int slot = atomicAdd(&cellfill[b * NCELL + cid], 1);
  const int pos = b * NPTS + cellstart[b * 1729 + cid] + slot;
  qorder[pos] = pt;
  xyzs[pos] = make_float4(x, y, z, 0.f);
}

// ---------------------------------------------------------------------------
// Kf: feats -> sorted bf16 copy (gathered 32B reads, coalesced 16B writes)
// ---------------------------------------------------------------------------
__global__ __launch_bounds__(256) void kf_sortfeats(
    const float* __restrict__ feats, const int* __restrict__ qorder,
    unsigned short* __restrict__ fsorted)
{
  const int idx = blockIdx.x * 256 + threadIdx.x;  // 262144
  const int pos = idx >> 3, cg = idx & 7;
  const int q = qorder[pos];
  const float* src = &feats[(size_t)q * CIN + cg * 8];
  float4 a = *(const float4*)src, c = *(const float4*)(src + 4);
  union { unsigned short s[8]; uint4 v; } u;
  u.s[0] = f2bf(a.x); u.s[1] = f2bf(a.y); u.s[2] = f2bf(a.z); u.s[3] = f2bf(a.w);
  u.s[4] = f2bf(c.x); u.s[5] = f2bf(c.y); u.s[6] = f2bf(c.z); u.s[7] = f2bf(c.w);
  *(uint4*)&fsorted[(size_t)pos * CIN + cg * 8] = u.v;
}

// ---------------------------------------------------------------------------
// K2: fused ball-query + KPConv.  2048 blocks x 256 thr; block = 16
// consecutive *sorted* positions (spatially clustered).
//  p0) neighbor search: thread (q=tid>>4, s=tid&15<9) scans x-range of 3
//      cells (contiguous sorted positions!), LDS-atomic slot alloc.
//  p1) dense weight phase (rel from LDS, no gathers)
//  p2) accumulation: wave w -> queries w*4..+3, lane=channel; bf16 feats
//      gathers from sorted (L2-hot) positions; wf bf16 in LDS (A layout)
//  p3) MFMA 16x16x32 GEMM vs global Wt; epilogue: BN partials (shfl +
//      global fp32 atomics) + scattered row store via qm[].
// ---------------------------------------------------------------------------
__global__ __launch_bounds__(256, 2) void k2_conv(
    const float4* __restrict__ xyzs, const unsigned short* __restrict__ fsorted,
    const float* __restrict__ kpts, const int* __restrict__ cellstart,
    const int* __restrict__ qorder, const unsigned short* __restrict__ Wt,
    float* __restrict__ out, float* __restrict__ psum,
    float* __restrict__ psumsq)
{
  __shared__ short  wf[16][WFPAD];       // 30976 B
  __shared__ float  w2[16][MAXNN][16];   // 34816 B
  __shared__ float4 rel4[16][MAXNN];     //  8704 B
  __shared__ int    gidx[16][MAXNN];     //  2176 B
  __shared__ float4 qd[16];              //   256 B
  __shared__ int    qm[16];              //    64 B
  __shared__ int    cnts[16];            //    64 B
  __shared__ float  kp[NKP][4];          //   240 B

  const int tid = threadIdx.x;
  const int w   = tid >> 6;
  const int L   = tid & 63;
  const int m0  = blockIdx.x * 16;       // sorted-position base
  const int b   = m0 >> 12;              // whole block in one batch

  if (tid < NKP * 3) {
    int k = tid / 3, c = tid - k * 3;
    kp[k][c] = kpts[tid];
  }
  if (tid < 16) {
    qd[tid] = xyzs[m0 + tid];
    qm[tid] = qorder[m0 + tid];
    cnts[tid] = 0;
  }
  __syncthreads();

  // ---- p0: neighbor search over 9 contiguous x-ranges ----
  {
    const int q = tid >> 4, s = tid & 15;
    if (s < 9) {
      const float4 Q = qd[q];
      int cx = (int)(Q.x * 12.f); cx = cx > 11 ? 11 : cx;
      int cy = (int)(Q.y * 12.f); cy = cy > 11 ? 11 : cy;
      int cz = (int)(Q.z * 12.f); cz = cz > 11 ? 11 : cz;
      const int ny = cy + (s % 3) - 1;
      const int nz = cz + (s / 3) - 1;
      if (ny >= 0 && ny < 12 && nz >= 0 && nz < 12) {
        const int xlo = cx > 0 ? cx - 1 : 0;
        const int xhi = cx < 11 ? cx + 1 : 11;
        const int rowb = b * 1729 + (nz * 12 + ny) * 12;
        const int r0 = cellstart[rowb + xlo];
        const int r1 = cellstart[rowb + xhi + 1];
        for (int p = r0; p < r1; p++) {
          float4 P = xyzs[b * NPTS + p];
          float dx = P.x - Q.x, dy = P.y - Q.y, dz = P.z - Q.z;
          float d2 = dx * dx + dy * dy + dz * dz;
          if (d2 <= R2EFF) {
            int slot = atomicAdd(&cnts[q], 1);
            if (slot < MAXNN) {
              gidx[q][slot] = b * NPTS + p;
              rel4[q][slot] = make_float4(dx, dy, dz, 0.f);
            }
          }
        }
      }
    }
  }
  __syncthreads();

  // ---- p1: dense weight phase (544 pairs over 256 threads) ----
  #pragma unroll
  for (int rep = 0; rep < 3; rep++) {
    const int p = rep * 256 + tid;
    if (p < 16 * MAXNN) {
      const int q  = (p * 241) >> 13;     // p / 34
      const int nn = p - q * MAXNN;
      int c = cnts[q]; c = c > MAXNN ? MAXNN : c;
      if (nn < c) {
        const float4 R = rel4[q][nn];
        float wv[16];
        #pragma unroll
        for (int k = 0; k < NKP; k++) {
          float dx = R.x - kp[k][0], dy = R.y - kp[k][1], dz = R.z - kp[k][2];
          float s = sqrtf(dx * dx + dy * dy + dz * dz);
          wv[k] = fmaxf(1.f - s * KP_INV, 0.f);
        }
        wv[15] = 0.f;
        float* dst = w2[q][nn];
        *(float4*)(dst + 0)  = *(float4*)(wv + 0);
        *(float4*)(dst + 4)  = *(float4*)(wv + 4);
        *(float4*)(dst + 8)  = *(float4*)(wv + 8);
        *(float4*)(dst + 12) = *(float4*)(wv + 12);
      }
    }
  }
  __syncthreads();

  // ---- p2: accumulation ----
  for (int qi = 0; qi < 4; qi++) {
    const int q = w * 4 + qi;
    int cnt = cnts[q]; cnt = cnt > MAXNN ? MAXNN : cnt;
    float acc[NKP];
    #pragma unroll
    for (int k = 0; k < NKP; k++) acc[k] = 0.f;

    int nn = 0;
    for (; nn + 2 <= cnt; nn += 2) {
      const float f0 = bf2f(fsorted[(size_t)gidx[q][nn] * CIN + L]);
      const float f1 = bf2f(fsorted[(size_t)gidx[q][nn + 1] * CIN + L]);
      const float* r0 = w2[q][nn];
      const float* r1 = w2[q][nn + 1];
      float4 a0 = *(const float4*)(r0 + 0), a1 = *(const float4*)(r0 + 4);
      float4 a2 = *(const float4*)(r0 + 8), a3 = *(const float4*)(r0 + 12);
      float4 b0 = *(const float4*)(r1 + 0), b1 = *(const float4*)(r1 + 4);
      float4 b2 = *(const float4*)(r1 + 8), b3 = *(const float4*)(r1 + 12);
      acc[0]  += a0.x * f0 + b0.x * f1;  acc[1]  += a0.y * f0 + b0.y * f1;
      acc[2]  += a0.z * f0 + b0.z * f1;  acc[3]  += a0.w * f0 + b0.w * f1;
      acc[4]  += a1.x * f0 + b1.x * f1;  acc[5]  += a1.y * f0 + b1.y * f1;
      acc[6]  += a1.z * f0 + b1.z * f1;  acc[7]  += a1.w * f0 + b1.w * f1;
      acc[8]  += a2.x * f0 + b2.x * f1;  acc[9]  += a2.y * f0 + b2.y * f1;
      acc[10] += a2.z * f0 + b2.z * f1;  acc[11] += a2.w * f0 + b2.w * f1;
      acc[12] += a3.x * f0 + b3.x * f1;  acc[13] += a3.y * f0 + b3.y * f1;
      acc[14] += a3.z * f0 + b3.z * f1;
    }
    if (nn < cnt) {
      const float f0 = bf2f(fsorted[(size_t)gidx[q][nn] * CIN + L]);
      const float* r0 = w2[q][nn];
      float4 a0 = *(const float4*)(r0 + 0), a1 = *(const float4*)(r0 + 4);
      float4 a2 = *(const float4*)(r0 + 8), a3 = *(const float4*)(r0 + 12);
      acc[0]  += a0.x * f0;  acc[1]  += a0.y * f0;
      acc[2]  += a0.z * f0;  acc[3]  += a0.w * f0;
      acc[4]  += a1.x * f0;  acc[5]  += a1.y * f0;
      acc[6]  += a1.z * f0;  acc[7]  += a1.w * f0;
      acc[8]  += a2.x * f0;  acc[9]  += a2.y * f0;
      acc[10] += a2.z * f0;  acc[11] += a2.w * f0;
      acc[12] += a3.x * f0;  acc[13] += a3.y * f0;
      acc[14] += a3.z * f0;
    }
    #pragma unroll
    for (int k = 0; k < NKP; k++)
      wf[q][k * 64 + L] = (short)f2bf(acc[k]);
  }
  __syncthreads();

  // ---- p3: MFMA GEMM out[16][128] = wf[16][960] @ W[960][128] ----
  const int ln = L & 15;
  const int kh = L >> 4;            // 0..3
  const int colbase = w * 32;

  f32x4_t acc2[2];
  acc2[0] = (f32x4_t){0.f, 0.f, 0.f, 0.f};
  acc2[1] = (f32x4_t){0.f, 0.f, 0.f, 0.f};

  const unsigned short* Bp0 = &Wt[(size_t)(colbase + ln) * KTOT + kh * 8];
  const unsigned short* Bp1 = Bp0 + 16 * KTOT;
  const short* Ap = &wf[ln][kh * 8];

  #pragma unroll 3
  for (int kk = 0; kk < 30; kk++) {
    const int ko = kk * 32;
    bf16x8_t b0 = *(const bf16x8_t*)(Bp0 + ko);
    bf16x8_t b1 = *(const bf16x8_t*)(Bp1 + ko);
    bf16x8_t a0 = *(const bf16x8_t*)(Ap + ko);
    acc2[0] = __builtin_amdgcn_mfma_f32_16x16x32_bf16(a0, b0, acc2[0], 0, 0, 0);
    acc2[1] = __builtin_amdgcn_mfma_f32_16x16x32_bf16(a0, b1, acc2[1], 0, 0, 0);
  }

  // BN partials: reduce 16 rows across kh via shfl, atomic into psum[128]
  float s0 = 0.f, q0 = 0.f, s1 = 0.f, q1 = 0.f;
  #pragma unroll
  for (int j = 0; j < 4; j++) {
    s0 += acc2[0][j]; q0 += acc2[0][j] * acc2[0][j];
    s1 += acc2[1][j]; q1 += acc2[1][j] * acc2[1][j];
  }
  s0 += __shfl_xor(s0, 16); s0 += __shfl_xor(s0, 32);
  q0 += __shfl_xor(q0, 16); q0 += __shfl_xor(q0, 32);
  s1 += __shfl_xor(s1, 16); s1 += __shfl_xor(s1, 32);
  q1 += __shfl_xor(q1, 16); q1 += __shfl_xor(q1, 32);
  if (kh == 0) {
    atomicAdd(&psum[colbase + ln], s0);
    atomicAdd(&psumsq[colbase + ln], q0);
    atomicAdd(&psum[colbase + 16 + ln], s1);
    atomicAdd(&psumsq[colbase + 16 + ln], q1);
  }

  // C/D layout: col = lane&15, row = (lane>>4)*4 + reg; scatter via qm[]
  #pragma unroll
  for (int c = 0; c < 2; c++) {
    #pragma unroll
    for (int j = 0; j < 4; j++) {
      const int row = kh * 4 + j;
      out[(size_t)qm[row] * COUT + colbase + c * 16 + ln] = acc2[c][j];
    }
  }
}

// ---------------------------------------------------------------------------
// K3b: finalize mu/var -> per-channel affine (a, b)
// ---------------------------------------------------------------------------
__global__ void k3b_finalize(
    const float* __restrict__ psum, const float* __restrict__ psumsq,
    const float* __restrict__ gamma, const float* __restrict__ beta,
    float* __restrict__ ab)
{
  const int d = threadIdx.x;  // 128 threads
  double mu  = (double)psum[d] / (double)M_TOT;
  double var = (double)psumsq[d] / (double)M_TOT - mu * mu;  // biased (jnp.var)
  float rstd = (float)(1.0 / sqrt(var + 1e-5));
  float a = rstd * gamma[d];
  ab[d]       = a;
  ab[128 + d] = beta[d] - (float)mu * a;
}

// K4: y = a[d]*x + b[d]; LeakyReLU
__global__ __launch_bounds__(256) void k4_norm(
    float* __restrict__ out, const float* __restrict__ ab)
{
  __shared__ float a_s[128], b_s[128];
  if (threadIdx.x < 128) {
    a_s[threadIdx.x] = ab[threadIdx.x];
    b_s[threadIdx.x] = ab[128 + threadIdx.x];
  }
  __syncthreads();
  const int idx = blockIdx.x * 256 + threadIdx.x;   // float4 index
  float4 v = ((const float4*)out)[idx];
  const int d0 = (idx * 4) & 127;
  float y0 = v.x * a_s[d0 + 0] + b_s[d0 + 0];
  float y1 = v.y * a_s[d0 + 1] + b_s[d0 + 1];
  float y2 = v.z * a_s[d0 + 2] + b_s[d0 + 2];
  float y3 = v.w * a_s[d0 + 3] + b_s[d0 + 3];
  v.x = y0 >= 0.f ? y0 : NEG_SLOPE * y0;
  v.y = y1 >= 0.f ? y1 : NEG_SLOPE * y1;
  v.z = y2 >= 0.f ? y2 : NEG_SLOPE * y2;
  v.w = y3 >= 0.f ? y3 : NEG_SLOPE * y3;
  ((float4*)out)[idx] = v;
}

// ---------------------------------------------------------------------------
extern "C" void kernel_launch(void* const* d_in, const int* in_sizes, int n_in,
                              void* d_out, int out_size, void* d_ws,
                              size_t ws_size, hipStream_t stream)
{
  const float* xyz   = (const float*)d_in[0];
  const float* feats = (const float*)d_in[1];
  const float* kpts  = (const float*)d_in[2];
  const float* W     = (const float*)d_in[3];
  const float* gamma = (const float*)d_in[4];
  const float* beta  = (const float*)d_in[5];
  float* out = (float*)d_out;

  char* ws = (char*)d_ws;
  int*            cellcnt   = (int*)(ws + 0);           //  55296 B ─┐
  int*            cellfill  = (int*)(ws + 55296);       //  55296 B  │ zeroed
  float*          psum      = (float*)(ws + 110592);    //    512 B  │ together
  float*          psumsq    = (float*)(ws + 111104);    //    512 B ─┘
  int*            cellstart = (int*)(ws + 111616);      //  55424 B (8*1729*4)
  int*            qorder    = (int*)(ws + 167040);      // 131072 B
  float4*         xyzs      = (float4*)(ws + 298112);   // 524288 B
  unsigned short* fsorted   = (unsigned short*)(ws + 822400);   // 4194304 B
  float*          ab        = (float*)(ws + 5016704);   //   1024 B
  unsigned short* Wt        = (unsigned short*)(ws + 5017728);  // 245760 B

  hipMemsetAsync(ws, 0, 111616, stream);

  k0a_hist   <<<128, 256, 0, stream>>>(xyz, cellcnt);
  k0b_scan_kW<<< 68, 256, 0, stream>>>(cellcnt, cellstart, W, Wt);
  k0c_scatter<<<128, 256, 0, stream>>>(xyz, cellstart, cellfill, qorder, xyzs);
  kf_sortfeats<<<1024, 256, 0, stream>>>(feats, qorder, fsorted);
  k2_conv    <<<2048, 256, 0, stream>>>(xyzs, fsorted, kpts, cellstart, qorder,
                                        Wt, out, psum, psumsq);
  k3b_finalize<<<1, 128, 0, stream>>>(psum, psumsq, gamma, beta, ab);
  k4_norm    <<<(out_size / 4) / 256, 256, 0, stream>>>(out, ab);
}